// Round 6
// baseline (600.520 us; speedup 1.0000x reference)
//
#include <hip/hip_runtime.h>

#define DD 128
#define HH 160
#define WW 160
#define PLANE (DD * HH * WW)   // 3276800 voxels

// ---------------------------------------------------------------------------
// Pack: channel-major velocity -> interleaved xyz (stride 3 or 4 floats),
// prescaled by 2^-7 (exact power of two; commutes with all later roundings).
// ---------------------------------------------------------------------------
template<int STRIDE>
__global__ __launch_bounds__(256) void pack_kernel(const float* __restrict__ vel,
                                                   float* __restrict__ out) {
    int idx = blockIdx.x * blockDim.x + threadIdx.x;
    if (idx >= PLANE) return;
    const float s = 1.0f / 128.0f;
    float vx = __fmul_rn(vel[idx],             s);
    float vy = __fmul_rn(vel[idx + PLANE],     s);
    float vz = __fmul_rn(vel[idx + 2 * PLANE], s);
    if (STRIDE == 4) {
        float4 t; t.x = vx; t.y = vy; t.z = vz; t.w = 0.0f;
        ((float4*)out)[idx] = t;
    } else {
        float* p = out + idx * 3;
        p[0] = vx; p[1] = vy; p[2] = vz;
    }
}

// ---------------------------------------------------------------------------
// One scaling-and-squaring step on interleaved flow:
//   fout = f + trilinear_sample(f, id + f*100)
// Exact-_rn op chain in the reference's order (chaotic iteration => must
// bit-match numpy). Out-of-bounds corners (weight exactly 0 in the ref) are
// SKIPPED via per-lane exec masking: masked lanes issue no memory request,
// saving TA lane-address cycles (the measured bottleneck). Skipping a +/-0.0
// add can only change the sign of a zero -> absmax impact 0, and sign-of-zero
// is invisible downstream (x + 100*(-0) == x + 100*(+0)).
// ---------------------------------------------------------------------------
template<int STRIDE, bool DST_CM>
__global__ __launch_bounds__(256) void diffeo_step(const float* __restrict__ fin,
                                                   float* __restrict__ fout) {
    int idx = blockIdx.x * blockDim.x + threadIdx.x;
    if (idx >= PLANE) return;

    int x = idx % WW;
    int y = (idx / WW) % HH;
    int z = idx / (WW * HH);

    float fx, fy, fz;
    if (STRIDE == 4) {
        float4 t = ((const float4*)fin)[idx];
        fx = t.x; fy = t.y; fz = t.z;
    } else {
        const float* p = fin + idx * 3;
        fx = p[0]; fy = p[1]; fz = p[2];
    }

    // grid = sample_grid + flow*100  (separate mul + add, NO fma)
    float px = __fadd_rn((float)x, __fmul_rn(fx, 100.0f));
    float py = __fadd_rn((float)y, __fmul_rn(fy, 100.0f));
    float pz = __fadd_rn((float)z, __fmul_rn(fz, 100.0f));

    // normalize: (p - ext/2) / ext * 2   (ext = [159, 159, 127])
    float gx = __fmul_rn(__fdiv_rn(__fsub_rn(px, 79.5f), 159.0f), 2.0f);
    float gy = __fmul_rn(__fdiv_rn(__fsub_rn(py, 79.5f), 159.0f), 2.0f);
    float gz = __fmul_rn(__fdiv_rn(__fsub_rn(pz, 63.5f), 127.0f), 2.0f);

    // denormalize: ((g + 1) * 0.5) * (N-1)  — left-associated like the ref
    float ix = __fmul_rn(__fmul_rn(__fadd_rn(gx, 1.0f), 0.5f), 159.0f);
    float iy = __fmul_rn(__fmul_rn(__fadd_rn(gy, 1.0f), 0.5f), 159.0f);
    float iz = __fmul_rn(__fmul_rn(__fadd_rn(gz, 1.0f), 0.5f), 127.0f);

    float x0f = floorf(ix), y0f = floorf(iy), z0f = floorf(iz);
    int x0 = (int)x0f, y0 = (int)y0f, z0 = (int)z0f;

    int xc[2], yc[2], zc[2];
    bool xin[2], yin[2], zin[2];
#pragma unroll
    for (int d = 0; d < 2; ++d) {
        int xv = x0 + d, yv = y0 + d, zv = z0 + d;
        xin[d] = (xv >= 0) && (xv < WW);
        yin[d] = (yv >= 0) && (yv < HH);
        zin[d] = (zv >= 0) && (zv < DD);
        xc[d] = min(max(xv, 0), WW - 1);
        yc[d] = min(max(yv, 0), HH - 1);
        zc[d] = min(max(zv, 0), DD - 1);
    }

    float wx1 = __fsub_rn(ix, x0f);
    float wy1 = __fsub_rn(iy, y0f);
    float wz1 = __fsub_rn(iz, z0f);
    float wxa[2] = { __fsub_rn(1.0f, wx1), wx1 };
    float wya[2] = { __fsub_rn(1.0f, wy1), wy1 };
    float wza[2] = { __fsub_rn(1.0f, wz1), wz1 };

    // Gather all in-bounds corners (exec-masked loads; OOB lanes issue no
    // request). Destinations pre-zeroed; accumulation happens afterwards in
    // the reference's corner order (z outer, y mid, x inner).
    float cv[24];
    float cw[8];
#pragma unroll
    for (int dz = 0; dz < 2; ++dz) {
#pragma unroll
        for (int dy = 0; dy < 2; ++dy) {
#pragma unroll
            for (int dx = 0; dx < 2; ++dx) {
                int c = dz * 4 + dy * 2 + dx;
                bool inb = zin[dz] && yin[dy] && xin[dx];
                float vx = 0.0f, vy = 0.0f, vz = 0.0f;
                if (inb) {
                    int off = (zc[dz] * HH + yc[dy]) * WW + xc[dx];
                    if (STRIDE == 4) {
                        float4 t = ((const float4*)fin)[off];
                        vx = t.x; vy = t.y; vz = t.z;
                    } else {
                        const float* p = fin + off * 3;
                        vx = p[0]; vy = p[1]; vz = p[2];
                    }
                }
                cv[c * 3 + 0] = vx;
                cv[c * 3 + 1] = vy;
                cv[c * 3 + 2] = vz;
                // weight only consumed when inb (else the term is skipped)
                cw[c] = __fmul_rn(__fmul_rn(wza[dz], wya[dy]), wxa[dx]);
                if (!inb) cw[c] = 0.0f;
            }
        }
    }

    float sx = 0.0f, sy = 0.0f, sz = 0.0f;
#pragma unroll
    for (int c = 0; c < 8; ++c) {
        sx = __fadd_rn(sx, __fmul_rn(cv[c * 3 + 0], cw[c]));
        sy = __fadd_rn(sy, __fmul_rn(cv[c * 3 + 1], cw[c]));
        sz = __fadd_rn(sz, __fmul_rn(cv[c * 3 + 2], cw[c]));
    }

    float ox = __fadd_rn(fx, sx);
    float oy = __fadd_rn(fy, sy);
    float oz = __fadd_rn(fz, sz);

    if (DST_CM) {
        fout[idx]             = ox;
        fout[idx + PLANE]     = oy;
        fout[idx + 2 * PLANE] = oz;
    } else if (STRIDE == 4) {
        float4 t; t.x = ox; t.y = oy; t.z = oz; t.w = 0.0f;
        ((float4*)fout)[idx] = t;
    } else {
        float* p = fout + idx * 3;
        p[0] = ox; p[1] = oy; p[2] = oz;
    }
}

extern "C" void kernel_launch(void* const* d_in, const int* in_sizes, int n_in,
                              void* d_out, int out_size, void* d_ws, size_t ws_size,
                              hipStream_t stream) {
    const float* velocity = (const float*)d_in[0];

    const int threads = 256;
    const int blocks = (PLANE + threads - 1) / threads;

    const size_t padded_need = (size_t)PLANE * 16 * 2;  // two float4 buffers

    if (ws_size >= padded_need) {
        // Padded path: both ping-pong buffers (float4/voxel) live in ws.
        float* P0 = (float*)d_ws;
        float* P1 = (float*)d_ws + (size_t)PLANE * 4;
        float* out = (float*)d_out;

        pack_kernel<4><<<blocks, threads, 0, stream>>>(velocity, P0);
        diffeo_step<4, false><<<blocks, threads, 0, stream>>>(P0, P1);  // s1
        diffeo_step<4, false><<<blocks, threads, 0, stream>>>(P1, P0);  // s2
        diffeo_step<4, false><<<blocks, threads, 0, stream>>>(P0, P1);  // s3
        diffeo_step<4, false><<<blocks, threads, 0, stream>>>(P1, P0);  // s4
        diffeo_step<4, false><<<blocks, threads, 0, stream>>>(P0, P1);  // s5
        diffeo_step<4, false><<<blocks, threads, 0, stream>>>(P1, P0);  // s6
        diffeo_step<4, true ><<<blocks, threads, 0, stream>>>(P0, out); // s7 -> d_out CM
    } else {
        // Fallback (R4-proven): stride-3 interleaved, ping-pong ws <-> d_out.
        float* A = (float*)d_out;
        float* B = (float*)d_ws;

        pack_kernel<3><<<blocks, threads, 0, stream>>>(velocity, B);
        diffeo_step<3, false><<<blocks, threads, 0, stream>>>(B, A);  // s1
        diffeo_step<3, false><<<blocks, threads, 0, stream>>>(A, B);  // s2
        diffeo_step<3, false><<<blocks, threads, 0, stream>>>(B, A);  // s3
        diffeo_step<3, false><<<blocks, threads, 0, stream>>>(A, B);  // s4
        diffeo_step<3, false><<<blocks, threads, 0, stream>>>(B, A);  // s5
        diffeo_step<3, false><<<blocks, threads, 0, stream>>>(A, B);  // s6
        diffeo_step<3, true ><<<blocks, threads, 0, stream>>>(B, A);  // s7 -> d_out CM
    }
}

// Round 7
// 375.872 us; speedup vs baseline: 1.5977x; 1.5977x over previous
//
#include <hip/hip_runtime.h>

#define DD 128
#define HH 160
#define WW 160
#define PLANE (DD * HH * WW)   // 3276800 voxels

// ---------------------------------------------------------------------------
// Pack: channel-major velocity -> interleaved xyz (12 B/voxel), prescaled by
// 2^-7 (exact power of two; commutes with all later roundings).
// ---------------------------------------------------------------------------
__global__ __launch_bounds__(256) void pack_kernel(const float* __restrict__ vel,
                                                   float* __restrict__ out) {
    int idx = blockIdx.x * blockDim.x + threadIdx.x;
    if (idx >= PLANE) return;
    const float s = 1.0f / 128.0f;
    float vx = __fmul_rn(vel[idx],             s);
    float vy = __fmul_rn(vel[idx + PLANE],     s);
    float vz = __fmul_rn(vel[idx + 2 * PLANE], s);
    float* p = out + idx * 3;
    p[0] = vx; p[1] = vy; p[2] = vz;
}

// ---------------------------------------------------------------------------
// One scaling-and-squaring step, 12 B interleaved flow, TILED thread mapping:
//   wave = 16x4x1 voxel tile, block = 16x16x1, grid = (10, 10, 128).
// Gathers of a wave concentrate in a (16+2s)^2 x (1+2s) neighborhood around
// the tile (s = displacement sigma of the step) -> L1/L2 hits at mid steps.
// Per-voxel fp math identical to the linear version (bit-exact output).
//
// OOB corners (reference weight exactly 0) are skipped via exec-masked loads:
// inactive lanes issue no memory request (saves TA cycles + miss traffic).
// Skipping a +0.0 contribution is bit-safe.
// All fp ops use _rn intrinsics in the reference's exact order.
// ---------------------------------------------------------------------------
template<bool DST_CM>
__global__ __launch_bounds__(256) void diffeo_step(const float* __restrict__ fin,
                                                   float* __restrict__ fout) {
    int tx = threadIdx.x & 15;
    int ty = threadIdx.x >> 4;
    int x = blockIdx.x * 16 + tx;
    int y = blockIdx.y * 16 + ty;
    int z = blockIdx.z;
    int idx = (z * HH + y) * WW + x;

    const float* self = fin + idx * 3;
    float fx = self[0];
    float fy = self[1];
    float fz = self[2];

    // grid = sample_grid + flow*100  (separate mul + add, NO fma)
    float px = __fadd_rn((float)x, __fmul_rn(fx, 100.0f));
    float py = __fadd_rn((float)y, __fmul_rn(fy, 100.0f));
    float pz = __fadd_rn((float)z, __fmul_rn(fz, 100.0f));

    // normalize: (p - ext/2) / ext * 2   (ext = [159, 159, 127])
    float gx = __fmul_rn(__fdiv_rn(__fsub_rn(px, 79.5f), 159.0f), 2.0f);
    float gy = __fmul_rn(__fdiv_rn(__fsub_rn(py, 79.5f), 159.0f), 2.0f);
    float gz = __fmul_rn(__fdiv_rn(__fsub_rn(pz, 63.5f), 127.0f), 2.0f);

    // denormalize: ((g + 1) * 0.5) * (N-1)  — left-associated like the ref
    float ix = __fmul_rn(__fmul_rn(__fadd_rn(gx, 1.0f), 0.5f), 159.0f);
    float iy = __fmul_rn(__fmul_rn(__fadd_rn(gy, 1.0f), 0.5f), 159.0f);
    float iz = __fmul_rn(__fmul_rn(__fadd_rn(gz, 1.0f), 0.5f), 127.0f);

    float x0f = floorf(ix), y0f = floorf(iy), z0f = floorf(iz);
    int x0 = (int)x0f, y0 = (int)y0f, z0 = (int)z0f;

    bool xin[2], yin[2], zin[2];
#pragma unroll
    for (int d = 0; d < 2; ++d) {
        xin[d] = (x0 + d >= 0) && (x0 + d < WW);
        yin[d] = (y0 + d >= 0) && (y0 + d < HH);
        zin[d] = (z0 + d >= 0) && (z0 + d < DD);
    }

    float wx1 = __fsub_rn(ix, x0f);
    float wy1 = __fsub_rn(iy, y0f);
    float wz1 = __fsub_rn(iz, z0f);
    float wxa[2] = { __fsub_rn(1.0f, wx1), wx1 };
    float wya[2] = { __fsub_rn(1.0f, wy1), wy1 };
    float wza[2] = { __fsub_rn(1.0f, wz1), wz1 };

    // Exec-masked corner gathers; accumulate afterwards in the reference's
    // corner order (z outer, y mid, x inner).
    float cv[24];
    float cw[8];
#pragma unroll
    for (int dz = 0; dz < 2; ++dz) {
#pragma unroll
        for (int dy = 0; dy < 2; ++dy) {
#pragma unroll
            for (int dx = 0; dx < 2; ++dx) {
                int c = dz * 4 + dy * 2 + dx;
                bool inb = zin[dz] && yin[dy] && xin[dx];
                float vx = 0.0f, vy = 0.0f, vz = 0.0f;
                if (inb) {
                    const float* p = fin + (((z0 + dz) * HH + (y0 + dy)) * WW + (x0 + dx)) * 3;
                    vx = p[0]; vy = p[1]; vz = p[2];
                }
                cv[c * 3 + 0] = vx;
                cv[c * 3 + 1] = vy;
                cv[c * 3 + 2] = vz;
                float w = __fmul_rn(__fmul_rn(wza[dz], wya[dy]), wxa[dx]);
                cw[c] = inb ? w : 0.0f;
            }
        }
    }

    float sx = 0.0f, sy = 0.0f, sz = 0.0f;
#pragma unroll
    for (int c = 0; c < 8; ++c) {
        sx = __fadd_rn(sx, __fmul_rn(cv[c * 3 + 0], cw[c]));
        sy = __fadd_rn(sy, __fmul_rn(cv[c * 3 + 1], cw[c]));
        sz = __fadd_rn(sz, __fmul_rn(cv[c * 3 + 2], cw[c]));
    }

    float ox = __fadd_rn(fx, sx);
    float oy = __fadd_rn(fy, sy);
    float oz = __fadd_rn(fz, sz);

    if (DST_CM) {
        fout[idx]             = ox;
        fout[idx + PLANE]     = oy;
        fout[idx + 2 * PLANE] = oz;
    } else {
        float* p = fout + idx * 3;
        p[0] = ox; p[1] = oy; p[2] = oz;
    }
}

extern "C" void kernel_launch(void* const* d_in, const int* in_sizes, int n_in,
                              void* d_out, int out_size, void* d_ws, size_t ws_size,
                              hipStream_t stream) {
    const float* velocity = (const float*)d_in[0];
    float* A = (float*)d_out;  // interleaved scratch until the final step
    float* B = (float*)d_ws;   // interleaved scratch

    const int threads = 256;
    const int pack_blocks = (PLANE + threads - 1) / threads;
    dim3 tile_grid(WW / 16, HH / 16, DD);   // (10, 10, 128)

    pack_kernel<<<pack_blocks, threads, 0, stream>>>(velocity, B);

    // s1..s7 ping-pong; s7 reads B, writes d_out channel-major. Never aliased.
    diffeo_step<false><<<tile_grid, threads, 0, stream>>>(B, A);  // s1
    diffeo_step<false><<<tile_grid, threads, 0, stream>>>(A, B);  // s2
    diffeo_step<false><<<tile_grid, threads, 0, stream>>>(B, A);  // s3
    diffeo_step<false><<<tile_grid, threads, 0, stream>>>(A, B);  // s4
    diffeo_step<false><<<tile_grid, threads, 0, stream>>>(B, A);  // s5
    diffeo_step<false><<<tile_grid, threads, 0, stream>>>(A, B);  // s6
    diffeo_step<true ><<<tile_grid, threads, 0, stream>>>(B, A);  // s7 -> d_out
}